// Round 5
// baseline (192.635 us; speedup 1.0000x reference)
//
#include <hip/hip_runtime.h>
#include <stdint.h>
#include <stddef.h>

// EuclideanAttention MI355X, round 14.
// - flash: 64 q-rows per wave (4 Q-frag groups) -> each K/V ds_read_b128
//   feeds FOUR MFMAs; block = 256 q-rows, grid (8,32)=256 blocks = 1/CU.
//   Per-CU LDS read traffic (the measured dominant shared-resource term,
//   ~2250/3650 cyc at r13) halves to ~1100. Single barrier per chunk,
//   K[4]/V[4] quad-buffer, stage(c+3) issued first, vmcnt(8) drain-late
//   (2 chunks always in flight). No cross-chunk QK state (regs), no setprio
//   (1 wave/SIMD). XCD swizzle kept (r12: FETCH 70.7->12.5MB).
// - GEMMs + prep: identical to r13.

#define LOG2E 1.44269504088896f

typedef __attribute__((ext_vector_type(8))) short bf16x8;
typedef __attribute__((ext_vector_type(4))) float f32x4;
typedef __attribute__((ext_vector_type(4))) unsigned short u16x4;

__device__ __forceinline__ unsigned short f2b(float f) {
  union { float f; unsigned int u; } x; x.f = f;
  unsigned int u = x.u;
  u += 0x7fffu + ((u >> 16) & 1u);   // RNE
  return (unsigned short)(u >> 16);
}
__device__ __forceinline__ float b2f(unsigned short s) {
  union { unsigned int u; float f; } x; x.u = ((unsigned int)s) << 16;
  return x.f;
}
__device__ __forceinline__ unsigned int fbits(float f) {
  union { float f; unsigned int u; } x; x.f = f; return x.u;
}

// async global->LDS, 16B per lane. LDS dest = wave-uniform base + lane*16.
#define GLD_LDS(g, l) __builtin_amdgcn_global_load_lds( \
    (const __attribute__((address_space(1))) void*)(g), \
    (__attribute__((address_space(3))) void*)(l), 16, 0, 0)

// ------------------------------------------------- prep: W transpose + X cvt
__global__ void prep_kernel(const float* __restrict__ X,
                            const float* __restrict__ wq, const float* __restrict__ wk,
                            const float* __restrict__ wv, const float* __restrict__ wo,
                            unsigned short* __restrict__ Xb,
                            unsigned short* __restrict__ WTqkv, unsigned short* __restrict__ WTo) {
  int z = blockIdx.z;
  if (z == 4) {
    size_t base = ((size_t)(blockIdx.y * 16 + blockIdx.x)) * 16384;
    #pragma unroll
    for (int j = 0; j < 16; ++j) {
      size_t i = base + (size_t)(j * 256 + threadIdx.x) * 4;
      f32x4 v = *(const f32x4*)&X[i];
      u16x4 o;
      #pragma unroll
      for (int k = 0; k < 4; ++k) o[k] = f2b(v[k]);
      *(u16x4*)&Xb[i] = o;
    }
    return;
  }
  __shared__ float tile[64][65];
  const float* src = (z == 0) ? wq : (z == 1) ? wk : (z == 2) ? wv : wo;
  unsigned short* dst = (z < 3) ? (WTqkv + (size_t)z * 1024 * 1024) : WTo;
  int k0 = blockIdx.y * 64, n0 = blockIdx.x * 64;
  int rr = threadIdx.x >> 6, cc = threadIdx.x & 63;
  #pragma unroll
  for (int p = 0; p < 16; ++p) {
    int row = p * 4 + rr;
    tile[row][cc] = src[(size_t)(k0 + row) * 1024 + n0 + cc];
  }
  __syncthreads();
  #pragma unroll
  for (int p = 0; p < 16; ++p) {
    int row = p * 4 + rr;                       // n offset
    dst[(size_t)(n0 + row) * 1024 + k0 + cc] = f2b(tile[cc][row]);
  }
}

// -------------------------------------------------------------- QKV GEMM
// C[4096,3072] = X @ [wq|wk|wv] + bias. 128x128 tile, BK=64 two-stage,
// 3 blocks/CU. K epilogue emits pre-scaled ||row||^2 (* log2e/T). V epilogue
// LDS-transposes into permuted VT (pos = G*32+q4*8+sub*4+i) with coalesced writes.
__global__ __launch_bounds__(256, 3) void gemm_qkv_kernel(
    const unsigned short* __restrict__ X, const unsigned short* __restrict__ WT,
    const float* __restrict__ bq, const float* __restrict__ bk, const float* __restrict__ bv,
    const float* __restrict__ temp,
    unsigned short* __restrict__ Qb, unsigned short* __restrict__ Kb,
    unsigned short* __restrict__ VTo, float* __restrict__ ks2) {
  __shared__ __align__(16) unsigned short smem[16896];   // As(8192) Bs(8192) | Vt alias
  unsigned short* As = smem;            // [kh<2][row<128][32]
  unsigned short* Bs = smem + 8192;
  const int t = threadIdx.x, w = t >> 6, lane = t & 63;
  const int r = lane & 15, q4 = lane >> 4;
  const int m0 = blockIdx.y * 128, n0 = blockIdx.x * 128;
  const int wr = (w >> 1) * 64, wc = (w & 1) * 64;
  const unsigned short* Xg = X + (size_t)m0 * 1024;
  const unsigned short* Wg = WT + (size_t)n0 * 1024;
  f32x4 acc[4][4] = {};
  for (int k0 = 0; k0 < 1024; k0 += 64) {
    #pragma unroll
    for (int g = 0; g < 4; ++g) {
      int slot = g * 256 + t;
      int kh = slot >> 9, row = (slot >> 2) & 127, ko = (slot & 3) * 8;
      GLD_LDS(Xg + (size_t)row * 1024 + k0 + kh * 32 + ko, &As[(g * 256 + w * 64) * 8]);
      GLD_LDS(Wg + (size_t)row * 1024 + k0 + kh * 32 + ko, &Bs[(g * 256 + w * 64) * 8]);
    }
    __syncthreads();
    #pragma unroll
    for (int kh = 0; kh < 2; ++kh) {
      bf16x8 af[4], bfr[4];
      #pragma unroll
      for (int mf = 0; mf < 4; ++mf)
        af[mf] = *(const bf16x8*)&As[kh * 4096 + (wr + mf * 16 + r) * 32 + q4 * 8];
      #pragma unroll
      for (int nf = 0; nf < 4; ++nf)
        bfr[nf] = *(const bf16x8*)&Bs[kh * 4096 + (wc + nf * 16 + r) * 32 + q4 * 8];
      #pragma unroll
      for (int mf = 0; mf < 4; ++mf)
        #pragma unroll
        for (int nf = 0; nf < 4; ++nf)
          acc[mf][nf] = __builtin_amdgcn_mfma_f32_16x16x32_bf16(af[mf], bfr[nf], acc[mf][nf], 0, 0, 0);
    }
    __syncthreads();
  }
  const int nblk = n0 >> 10;
  if (nblk == 0) {
    // Q: plain bf16 store (q^2 shift cancels in softmax)
    const int nc0 = n0 & 1023;
    #pragma unroll
    for (int nf = 0; nf < 4; ++nf) {
      int n = nc0 + wc + nf * 16 + r;
      float bb = bq[n];
      #pragma unroll
      for (int mf = 0; mf < 4; ++mf) {
        int m = m0 + wr + mf * 16 + q4 * 4;
        f32x4 v = acc[mf][nf];
        #pragma unroll
        for (int i = 0; i < 4; ++i)
          Qb[(size_t)(m + i) * 1024 + n] = f2b(v[i] + bb);
      }
    }
  } else if (nblk == 1) {
    const float sc = LOG2E / temp[0];
    const int nc0 = n0 & 1023;
    float s2a[4][4] = {};
    #pragma unroll
    for (int nf = 0; nf < 4; ++nf) {
      int n = nc0 + wc + nf * 16 + r;
      float bb = bk[n];
      #pragma unroll
      for (int mf = 0; mf < 4; ++mf) {
        int m = m0 + wr + mf * 16 + q4 * 4;
        f32x4 v = acc[mf][nf];
        #pragma unroll
        for (int i = 0; i < 4; ++i) {
          unsigned short os = f2b(v[i] + bb);
          Kb[(size_t)(m + i) * 1024 + n] = os;
          float xb = b2f(os);
          s2a[mf][i] += xb * xb;          // sum of squares of the ROUNDED value
        }
      }
    }
    #pragma unroll
    for (int mf = 0; mf < 4; ++mf)
      #pragma unroll
      for (int i = 0; i < 4; ++i) {
        float v = s2a[mf][i];
        v += __shfl_xor(v, 1, 64);
        v += __shfl_xor(v, 2, 64);
        v += __shfl_xor(v, 4, 64);
        v += __shfl_xor(v, 8, 64);
        s2a[mf][i] = v * sc;
      }
    if (r == 0) {
      int hh = (nc0 + wc) >> 6;
      #pragma unroll
      for (int mf = 0; mf < 4; ++mf) {
        int m = m0 + wr + mf * 16 + q4 * 4;
        int bb2 = m >> 11, ss = m & 2047;
        #pragma unroll
        for (int i = 0; i < 4; ++i)
          ks2[(size_t)(bb2 * 16 + hh) * 2048 + ss + i] = s2a[mf][i];
      }
    }
  } else {
    // ---- V: LDS transpose -> permuted, coalesced VT writes (Vt aliases As/Bs)
    unsigned short* Vt = smem;          // [head<2][d<64][G<2 * pos<64], stride 132
    const int c0 = n0 - 2048;
    const int head = w & 1;             // == wc>>6
    #pragma unroll
    for (int nf = 0; nf < 4; ++nf) {
      int c = c0 + wc + nf * 16 + r;
      float bb = bv[c];
      int d = c & 63;
      #pragma unroll
      for (int mf = 0; mf < 4; ++mf) {
        int mloc = wr + mf * 16 + q4 * 4;     // 0..124
        int G = mloc >> 6;
        int k6 = mloc & 63;
        int pos = (k6 >> 5) * 32 + ((k6 & 15) >> 2) * 8 + ((k6 >> 4) & 1) * 4;
        f32x4 v = acc[mf][nf];
        u16x4 pk;
        #pragma unroll
        for (int i = 0; i < 4; ++i) pk[i] = f2b(v[i] + bb);
        *(u16x4*)&Vt[(head * 64 + d) * 132 + G * 64 + pos] = pk;
      }
    }
    __syncthreads();
    int row = t >> 1, ch = t & 1;
    int hd = row >> 6, dd = row & 63;
    int hglob = (c0 >> 6) + hd;
    int bb2 = m0 >> 11, s0 = m0 & 2047;
    unsigned short* dst = &VTo[((size_t)((bb2 * 16 + hglob) * 64 + dd)) * 2048 + s0 + ch * 64];
    const unsigned short* srcL = &Vt[(hd * 64 + dd) * 132 + ch * 64];
    #pragma unroll
    for (int k2 = 0; k2 < 16; ++k2)
      *(u16x4*)&dst[k2 * 4] = *(const u16x4*)&srcL[k2 * 4];
  }
}

// ---------------------------------------------------------------- flash
// Block = (bh, 256 q-rows), 4 waves x 64 rows (4 Q-frag groups/wave).
// Grid (8,32)=256 blocks = 1/CU, XCD-swizzled (bh == wgid mod 8; per-XCD KV
// 2MB L2-resident, r12-verified). 64-key chunks, K[4]/V[4] quad-buffer.
// ONE barrier per chunk: issue stage(c+3) -> QK(c) -> exp(c) -> PV(c) ->
// vmcnt(8) [drains stage(c+1); c+2,c+3 stay in flight] -> s_barrier.
// Each K/V ds_read_b128 feeds 4 MFMAs (4 q-groups) -> per-CU LDS read
// traffic halves vs r13. ks2 pre-staged to LDS.
// p = exp2((2qk - k^2)*log2e/T)  (q^2 shift cancels; bounded by ~8)
__global__ __launch_bounds__(256, 1) void flash_kernel(
    const unsigned short* __restrict__ Qb, const unsigned short* __restrict__ Kb,
    const unsigned short* __restrict__ VT, const float* __restrict__ ks2,
    const float* __restrict__ temp, unsigned short* __restrict__ AO) {
  __shared__ __align__(16) unsigned short Ks[4][64 * 64];   // [buf][khalf<2][key<64][dd<32]
  __shared__ __align__(16) unsigned short Vs[4][64 * 64];   // [buf] XOR-swizzled 16B units
  __shared__ __align__(16) float KQs[2048];                 // pre-scaled k^2 for this bh
  const int t = threadIdx.x, w = t >> 6, lane = t & 63;
  const int r = lane & 15, q4 = lane >> 4;
  // XCD-aware swizzle: wgid%8 -> XCD; all 8 q-blocks of a bh on one XCD.
  const int wgid = blockIdx.x + 8 * blockIdx.y;    // [0,256)
  const int xcd = wgid & 7, s = wgid >> 3;         // s in [0,32)
  const int bh = xcd + 8 * (s & 3);                // 4 bh per XCD
  const int b = bh >> 4, h = bh & 15;
  const int q0 = (s >> 2) * 256;                   // 8 q-chunks per bh
  const float cc = 2.0f * LOG2E / temp[0];

  // Q fragments (B-operand: n=qrow=lane&15, k=q4*8+j); wave w owns rows
  // q0+w*64 .. +63 as four 16-row groups qg.
  bf16x8 qf[4][2];
  #pragma unroll
  for (int qg = 0; qg < 4; ++qg) {
    int sq = q0 + w * 64 + qg * 16 + r;
    const unsigned short* qp = Qb + (size_t)(b * 2048 + sq) * 1024 + h * 64;
    #pragma unroll
    for (int ks = 0; ks < 2; ++ks) qf[qg][ks] = *(const bf16x8*)(qp + ks * 32 + q4 * 8);
  }

  f32x4 accO[4][4] = {};
  f32x4 lsum[4] = {};
  bf16x8 ones;
  #pragma unroll
  for (int j = 0; j < 8; ++j) ones[j] = (short)0x3F80;   // bf16 1.0

  const unsigned short* Kg = Kb + ((size_t)b * 2048) * 1024 + h * 64;
  const unsigned short* Vg = VT + ((size_t)bh * 64) * 2048;
  const float* kqb = ks2 + bh * 2048;

  // per-lane staging sources (identical slot math to r9-r13; advance per chunk)
  const unsigned short* kp0 = Kg + (size_t)(t >> 2) * 1024 + (t & 3) * 8;  // khalf 0
  const unsigned short* kp1 = kp0 + 32;                                    // khalf 1
  int dd0 = t >> 3;
  const unsigned short* vp0 = Vg + (size_t)dd0 * 2048 + ((t & 7) ^ (dd0 & 7)) * 8;
  const unsigned short* vp1 = vp0 + (size_t)32 * 2048;

  // ---- prologue: ks2 -> LDS, stage chunks 0..2 (issue 14 loads total)
  GLD_LDS(kqb + t * 4, &KQs[t * 4]);
  GLD_LDS(kqb + 1024 + t * 4, &KQs[1024 + t * 4]);
  #pragma unroll
  for (int pc = 0; pc < 3; ++pc) {
    GLD_LDS(kp0, &Ks[pc][t * 8]);
    GLD_LDS(kp1, &Ks[pc][(256 + t) * 8]);
    GLD_LDS(vp0, &Vs[pc][t * 8]);
    GLD_LDS(vp1, &Vs[pc][(256 + t) * 8]);
    kp0 += 65536; kp1 += 65536; vp0 += 64; vp1 += 64;
  }
  // drain ks2 + stage0 (leaves stage1+stage2 = 8 in flight)
  asm volatile("s_waitcnt vmcnt(8)" ::: "memory");
  __builtin_amdgcn_s_barrier();
  __builtin_amdgcn_sched_barrier(0);

  // ---- main loop: ONE barrier per chunk. Body(c), J = c&3 (static):
  //  1. issue stage(c+3) -> Ks[(J+3)&3]/Vs[(J+3)&3]   (c<29)
  //  2. QK(c) from Ks[J] (transient st regs)
  //  3. exp(c) via KQs  4. PV(c) from Vs[J]
  //  5. vmcnt(8): drain stage(c+1); stage(c+2,c+3) stay in flight
  //  6. s_barrier (+sched_barrier pin)
#define CHUNK_BODY(C, J)                                                      \
  {                                                                           \
    const int c_ = (C);                                                       \
    if (c_ < 29) {                                                            \
      GLD_LDS(kp0, &Ks[((J) + 3) & 3][t * 8]);                                \
      GLD_LDS(kp1, &Ks[((J) + 3) & 3][(256 + t) * 8]);                        \
      GLD_LDS(vp0, &Vs[((J) + 3) & 3][t * 8]);                                \
      GLD_LDS(vp1, &Vs[((J) + 3) & 3][(256 + t) * 8]);                        \
      kp0 += 65536; kp1 += 65536; vp0 += 64; vp1 += 64;                       \
    }                                                                         \
    /* QK(c): A=K-frag (m=key), B=Q-frag (n=qrow); 4 q-groups per read */     \
    f32x4 st[4][4];                                                           \
    {                                                                         \
      const f32x4 zz = {};                                                    \
      _Pragma("unroll")                                                       \
      for (int ks = 0; ks < 2; ++ks) {                                        \
        _Pragma("unroll")                                                     \
        for (int kfm = 0; kfm < 4; ++kfm) {                                   \
          bf16x8 ka = *(const bf16x8*)&Ks[(J)][(ks * 64 + kfm * 16 + r) * 32 + q4 * 8]; \
          _Pragma("unroll")                                                   \
          for (int qg = 0; qg < 4; ++qg)                                      \
            st[qg][kfm] = __builtin_amdgcn_mfma_f32_16x16x32_bf16(ka, qf[qg][ks], ks ? st[qg][kfm] : zz, 0, 0, 0); \
        }                                                                     \
      }                                                                       \
    }                                                                         \
    /* exp(c): p = exp2(cc*qk - k2s); trunc-pack to pf[qg][cb] */             \
    f32x4 kq[4];                                                              \
    _Pragma("unroll")                                                         \
    for (int kfm = 0; kfm < 4; ++kfm)                                         \
      kq[kfm] = *(const f32x4*)&KQs[c_ * 64 + kfm * 16 + q4 * 4];             \
    bf16x8 pf[4][2];                                                          \
    _Pragma("unroll")                                                         \
    for (int qg = 0; qg < 4; ++qg) {                                          \
      _Pragma("unroll")                                                       \
      for (int cb = 0; cb < 2; ++cb) {                                        \
        unsigned int dw[4];                                                   \
        _Pragma("unroll")                                                     \
        for (int half = 0; half < 2; ++half) {                                \
          int kfm = cb * 2 + half;                                            \
          float pp[4];                                                        \
          _Pragma("unroll")                                                   \
          for (int i = 0; i < 4; ++i) {                                       \
            float u = __builtin_fmaf(cc, st[qg][kfm][i], -kq[kfm][i]);        \
            pp[i] = __builtin_amdgcn_exp2f(u);                                \
          }                                                                   \
          dw[half * 2 + 0] = (fbits(pp[0]) >> 16) | (fbits(pp[1]) & 0xFFFF0000u); \
          dw[half * 2 + 1] = (fbits(pp[2]) >> 16) | (fbits(pp[3]) & 0xFFFF0000u); \
        }                                                                     \
        union { unsigned int d[4]; bf16x8 v; } cv;                            \
        cv.d[0] = dw[0]; cv.d[1] = dw[1]; cv.d[2] = dw[2]; cv.d[3] = dw[3];   \
        pf[qg][cb] = cv.v;                                                    \
      }                                                                       \
    }                                                                         \
    /* PV(c): O += P.V ; lsum += P.ones (each V b128 feeds 4 q-groups) */     \
    _Pragma("unroll")                                                         \
    for (int cb = 0; cb < 2; ++cb) {                                          \
      _Pragma("unroll")                                                       \
      for (int qg = 0; qg < 4; ++qg)                                          \
        lsum[qg] = __builtin_amdgcn_mfma_f32_16x16x32_bf16(pf[qg][cb], ones, lsum[qg], 0, 0, 0); \
      _Pragma("unroll")                                                       \
      for (int df = 0; df < 4; ++df) {                                        \
        int dloc = df * 16 + r;                                               \
        int un = dloc * 8 + ((cb * 4 + q4) ^ (dloc & 7));                     \
        bf16x8 vb = *(const bf16x8*)&Vs[(J)][un * 8];                         \
        _Pragma("unroll")                                                     \
        for (int qg = 0; qg < 4; ++qg)                                        \
          accO[qg][df] = __builtin_amdgcn_mfma_f32_16x16x32_bf16(pf[qg][cb], vb, accO[qg][df], 0, 0, 0); \
      }                                                                       \
    }                                                                         \
    /* drain stage(c+1); keep c+2 (and c+3 if issued) in flight */            \
    if (c_ < 29)      { asm volatile("s_waitcnt vmcnt(8)" ::: "memory"); }    \
    else if (c_ == 29){ asm volatile("s_waitcnt vmcnt(4)" ::: "memory"); }    \
    else              { asm volatile("s_waitcnt vmcnt(0)" ::: "memory"); }    \
    __builtin_amdgcn_s_barrier();                                             \
    __builtin_amdgcn_sched_barrier(0);                                        \
  }

  for (int c4 = 0; c4 < 8; ++c4) {
    CHUNK_BODY(4 * c4 + 0, 0)
    CHUNK_BODY(4 * c4 + 1, 1)
    CHUNK_BODY(4 * c4 + 2, 2)
    CHUNK_BODY(4 * c4 + 3, 3)
  }
#undef CHUNK_BODY

  {
    #pragma unroll
    for (int qg = 0; qg < 4; ++qg) {
      float inv[4];
      #pragma unroll
      for (int i = 0; i < 4; ++i) inv[i] = 1.0f / lsum[qg][i];
      #pragma unroll
      for (int df = 0; df < 4; ++df) {
        int d = df * 16 + r;
        #pragma unroll
        for (int i = 0; i < 4; ++i) {
          int sq = q0 + w * 64 + qg * 16 + q4 * 4 + i;
          AO[(size_t)(b * 2048 + sq) * 1024 + h * 64 + d] = f2b(accO[qg][df][i] * inv[i]);
        }
      }
    }
  }
}

// ------------------------------------------------------------- out GEMM
// 128x64 tile, BK=64 two-stage, grid 16x32 = 512 blocks (2/CU).
__global__ __launch_bounds__(256, 2) void gemm_out_kernel(
    const unsigned short* __restrict__ A, const unsigned short* __restrict__ WT,
    const float* __restrict__ bo, float* __restrict__ Out) {
  __shared__ __align__(16) unsigned short As[2 * 128 * 32];   // [kh][row<128][32]
  __shared__ __align__(16) unsigned short Bs[2 * 64 * 32];    // [kh][row<64][32]
  const int t = threadIdx.x, w = t >> 6, lane = t & 63;
  const int r = lane & 15, q4 = lane >> 4;
  const int m0 = blockIdx.y * 128, n0 = blockIdx.x * 64;
  const int wr = (w >> 1) * 64, wc = (w & 1) * 32;
  const unsigned short* Ag = A + (size_t)m0 * 1024;
  const unsigned short* Wg = WT + (size_t)n0 * 1024;
  f32x4 acc[4][2] = {};
  for (int k0 = 0; k0 < 1024; k0 += 64) {
    #pragma unroll
    for (int g = 0; g < 4; ++g) {
      int slot = g * 256 + t;
      int kh = slot >> 9, row = (slot >> 2) & 127, ko = (slot & 3) * 8;
      GLD_LDS(Ag + (size_t)row * 1024 + k0 + kh * 32 + ko, &As[(g * 256 + w * 64) * 8]);
    }
    #pragma unroll
    for (int g = 0; g < 2; ++g) {
      int slot = g * 256 + t;
      int kh = slot >> 8, row = (slot >> 2) & 63, ko = (slot & 3) * 8;
      GLD_LDS(Wg + (size_t)row * 1024 + k0 + kh * 32 + ko, &Bs[(g * 256 + w * 64) * 8]);
    }
    __syncthreads();
    #pragma unroll
    for (int kh = 0; kh < 2; ++kh) {
      bf16x8 af[4], bfr[2];
      #pragma unroll
      for (int mf = 0; mf < 4; ++mf)
        af[mf] = *(const bf16x8*)&As[kh * 4096 + (wr + mf * 16 + r) * 32 + q4 * 8];
      #pragma unroll
      for (int nf = 0; nf < 2; ++nf)
        bfr[nf] = *(const bf16x8*)&Bs[kh * 2048 + (wc + nf * 16 + r) * 32 + q4 * 8];
      #pragma unroll
      for (int mf = 0; mf < 4; ++mf)
        #pragma unroll
        for (int nf = 0; nf < 2; ++nf)
          acc[mf][nf] = __builtin_amdgcn_mfma_f32_16x16x32_bf16(af[mf], bfr[nf], acc[mf][nf], 0, 0, 0);
    }
    __syncthreads();
  }
  #pragma unroll
  for (int nf = 0; nf < 2; ++nf) {
    int n = n0 + wc + nf * 16 + r;
    float bb = bo[n];
    #pragma unroll
    for (int mf = 0; mf < 4; ++mf) {
      int m = m0 + wr + mf * 16 + q4 * 4;
      f32x4 v = acc[mf][nf];
      #pragma unroll
      for (int i = 0; i < 4; ++i)
        Out[(size_t)(m + i) * 1024 + n] = v[i] + bb;
    }
  }
}

// ---------------------------------------------------------------- launch
extern "C" void kernel_launch(void* const* d_in, const int* in_sizes, int n_in,
                              void* d_out, int out_size, void* d_ws, size_t ws_size,
                              hipStream_t stream) {
  const float* X    = (const float*)d_in[0];
  const float* wq   = (const float*)d_in[1];
  const float* bq   = (const float*)d_in[2];
  const float* wk   = (const float*)d_in[3];
  const float* bk   = (const float*)d_in[4];
  const float* wv   = (const float*)d_in[5];
  const float* bv   = (const float*)d_in[6];
  const float* wo   = (const float*)d_in[7];
  const float* bo   = (const float*)d_in[8];
  const float* temp = (const float*)d_in[9];
  float* Out = (float*)d_out;

  char* ws = (char*)d_ws;
  unsigned short* Xb    = (unsigned short*)ws; ws += (size_t)4096 * 1024 * 2;
  unsigned short* WTqkv = (unsigned short*)ws; ws += (size_t)3072 * 1024 * 2;
  unsigned short* WTo   = (unsigned short*)ws; ws += (size_t)1024 * 1024 * 2;
  unsigned short* Qb    = (unsigned short*)ws; ws += (size_t)4096 * 1024 * 2;
  unsigned short* Kb    = (unsigned short*)ws; ws += (size_t)4096 * 1024 * 2;
  unsigned short* VT    = (unsigned short*)ws; ws += (size_t)4096 * 1024 * 2;
  float* ks2 = (float*)ws; ws += (size_t)65536 * 4;
  unsigned short* AO = Xb;   // Xb dead after gemm_qkv; reuse for flash output

  prep_kernel<<<dim3(16, 16, 5), 256, 0, stream>>>(X, wq, wk, wv, wo, Xb, WTqkv, WTo);
  gemm_qkv_kernel<<<dim3(24, 32), 256, 0, stream>>>(Xb, WTqkv, bq, bk, bv, temp, Qb, Kb, VT, ks2);
  flash_kernel<<<dim3(8, 32), 256, 0, stream>>>(Qb, Kb, VT, ks2, temp, AO);
  gemm_out_kernel<<<dim3(16, 32), 256, 0, stream>>>(AO, WTo, bo, Out);
}

// Round 6
// 184.948 us; speedup vs baseline: 1.0416x; 1.0416x over previous
//
#include <hip/hip_runtime.h>
#include <stdint.h>
#include <stddef.h>

// EuclideanAttention MI355X, round 15.
// - flash: exact r13 revert (proven best 48.7us; r14's 1-block/CU variant
//   regressed to 56.2 -- latency-bound, needs 8 waves/CU).
// - GEMMs: converted from 1-phase (stage -> syncthreads[vmcnt 0] -> compute)
//   to 2-deep latency-hidden pipeline: BK=32 half-steps, 3 half-buffers,
//   stage distance 2, ONE raw s_barrier + counted vmcnt(4/3) per half-step
//   (never 0 in steady state). Same barrier count (32), DMA latency now
//   covered by ~2 compute phases. qkv stays 3 blocks/CU (48KB LDS).
// - prep: identical.

#define LOG2E 1.44269504088896f

typedef __attribute__((ext_vector_type(8))) short bf16x8;
typedef __attribute__((ext_vector_type(4))) float f32x4;
typedef __attribute__((ext_vector_type(4))) unsigned short u16x4;

__device__ __forceinline__ unsigned short f2b(float f) {
  union { float f; unsigned int u; } x; x.f = f;
  unsigned int u = x.u;
  u += 0x7fffu + ((u >> 16) & 1u);   // RNE
  return (unsigned short)(u >> 16);
}
__device__ __forceinline__ float b2f(unsigned short s) {
  union { unsigned int u; float f; } x; x.u = ((unsigned int)s) << 16;
  return x.f;
}
__device__ __forceinline__ unsigned int fbits(float f) {
  union { float f; unsigned int u; } x; x.f = f; return x.u;
}

// async global->LDS, 16B per lane. LDS dest = wave-uniform base + lane*16.
#define GLD_LDS(g, l) __builtin_amdgcn_global_load_lds( \
    (const __attribute__((address_space(1))) void*)(g), \
    (__attribute__((address_space(3))) void*)(l), 16, 0, 0)

// ------------------------------------------------- prep: W transpose + X cvt
__global__ void prep_kernel(const float* __restrict__ X,
                            const float* __restrict__ wq, const float* __restrict__ wk,
                            const float* __restrict__ wv, const float* __restrict__ wo,
                            unsigned short* __restrict__ Xb,
                            unsigned short* __restrict__ WTqkv, unsigned short* __restrict__ WTo) {
  int z = blockIdx.z;
  if (z == 4) {
    size_t base = ((size_t)(blockIdx.y * 16 + blockIdx.x)) * 16384;
    #pragma unroll
    for (int j = 0; j < 16; ++j) {
      size_t i = base + (size_t)(j * 256 + threadIdx.x) * 4;
      f32x4 v = *(const f32x4*)&X[i];
      u16x4 o;
      #pragma unroll
      for (int k = 0; k < 4; ++k) o[k] = f2b(v[k]);
      *(u16x4*)&Xb[i] = o;
    }
    return;
  }
  __shared__ float tile[64][65];
  const float* src = (z == 0) ? wq : (z == 1) ? wk : (z == 2) ? wv : wo;
  unsigned short* dst = (z < 3) ? (WTqkv + (size_t)z * 1024 * 1024) : WTo;
  int k0 = blockIdx.y * 64, n0 = blockIdx.x * 64;
  int rr = threadIdx.x >> 6, cc = threadIdx.x & 63;
  #pragma unroll
  for (int p = 0; p < 16; ++p) {
    int row = p * 4 + rr;
    tile[row][cc] = src[(size_t)(k0 + row) * 1024 + n0 + cc];
  }
  __syncthreads();
  #pragma unroll
  for (int p = 0; p < 16; ++p) {
    int row = p * 4 + rr;                       // n offset
    dst[(size_t)(n0 + row) * 1024 + k0 + cc] = f2b(tile[cc][row]);
  }
}

// -------------------------------------------------------------- QKV GEMM
// C[4096,3072] = X @ [wq|wk|wv] + bias. 128x128 tile, BK=32 half-steps,
// 3-buffer 2-deep pipeline, 1 barrier + vmcnt(4) per half-step, 3 blocks/CU.
// K epilogue emits pre-scaled ||row||^2; V epilogue LDS-transposes into
// permuted VT (Vt aliases the stage buffers after the final barrier).
__global__ __launch_bounds__(256, 3) void gemm_qkv_kernel(
    const unsigned short* __restrict__ X, const unsigned short* __restrict__ WT,
    const float* __restrict__ bq, const float* __restrict__ bk, const float* __restrict__ bv,
    const float* __restrict__ temp,
    unsigned short* __restrict__ Qb, unsigned short* __restrict__ Kb,
    unsigned short* __restrict__ VTo, float* __restrict__ ks2) {
  __shared__ __align__(16) unsigned short smem3[24576];  // A3(12288) B3(12288) | Vt alias
#define AS3(j) (smem3 + (j) * 4096)
#define BS3(j) (smem3 + 12288 + (j) * 4096)
  const int t = threadIdx.x, w = t >> 6, lane = t & 63;
  const int r = lane & 15, q4 = lane >> 4;
  const int m0 = blockIdx.y * 128, n0 = blockIdx.x * 128;
  const int wr = (w >> 1) * 64, wc = (w & 1) * 64;
  const unsigned short* Xg = X + (size_t)m0 * 1024;
  const unsigned short* Wg = WT + (size_t)n0 * 1024;
  // per-thread stage sources (advance +32 per issued half-stage)
  const unsigned short* xs0 = Xg + (size_t)(t >> 2) * 1024 + (t & 3) * 8;
  const unsigned short* xs1 = xs0 + (size_t)64 * 1024;
  const unsigned short* ws0 = Wg + (size_t)(t >> 2) * 1024 + (t & 3) * 8;
  const unsigned short* ws1 = ws0 + (size_t)64 * 1024;
  f32x4 acc[4][4] = {};

#define QKV_STAGE(J2)                                     \
  {                                                       \
    GLD_LDS(xs0, &AS3(J2)[(w * 64) * 8]);                 \
    GLD_LDS(xs1, &AS3(J2)[(256 + w * 64) * 8]);           \
    GLD_LDS(ws0, &BS3(J2)[(w * 64) * 8]);                 \
    GLD_LDS(ws1, &BS3(J2)[(256 + w * 64) * 8]);           \
    xs0 += 32; xs1 += 32; ws0 += 32; ws1 += 32;           \
  }

  // prologue: stage half 0,1; drain half0 (leave half1 in flight)
  QKV_STAGE(0)
  QKV_STAGE(1)
  asm volatile("s_waitcnt vmcnt(4)" ::: "memory");
  __builtin_amdgcn_s_barrier();
  __builtin_amdgcn_sched_barrier(0);

#define QKV_BODY(J, STG, LAST)                                                \
  {                                                                           \
    if (STG) QKV_STAGE(((J) + 2) % 3)                                         \
    bf16x8 af[4], bfr[4];                                                     \
    _Pragma("unroll")                                                         \
    for (int mf = 0; mf < 4; ++mf)                                            \
      af[mf] = *(const bf16x8*)&AS3(J)[(wr + mf * 16 + r) * 32 + q4 * 8];     \
    _Pragma("unroll")                                                         \
    for (int nf = 0; nf < 4; ++nf)                                            \
      bfr[nf] = *(const bf16x8*)&BS3(J)[(wc + nf * 16 + r) * 32 + q4 * 8];    \
    _Pragma("unroll")                                                         \
    for (int mf = 0; mf < 4; ++mf)                                            \
      _Pragma("unroll")                                                       \
      for (int nf = 0; nf < 4; ++nf)                                          \
        acc[mf][nf] = __builtin_amdgcn_mfma_f32_16x16x32_bf16(af[mf], bfr[nf], acc[mf][nf], 0, 0, 0); \
    if (STG)       { asm volatile("s_waitcnt vmcnt(4)" ::: "memory"); }       \
    else if (!(LAST)) { asm volatile("s_waitcnt vmcnt(0)" ::: "memory"); }    \
    if (!(LAST)) {                                                            \
      __builtin_amdgcn_s_barrier();                                           \
      __builtin_amdgcn_sched_barrier(0);                                      \
    }                                                                         \
  }

  for (int hh = 0; hh < 5; ++hh) {      // half-steps 0..29 (all staging)
    QKV_BODY(0, 1, 0) QKV_BODY(1, 1, 0) QKV_BODY(2, 1, 0)
    QKV_BODY(0, 1, 0) QKV_BODY(1, 1, 0) QKV_BODY(2, 1, 0)
  }
  QKV_BODY(0, 0, 0)                     // h=30: drain st(31)
  QKV_BODY(1, 0, 1)                     // h=31: last
  __syncthreads();                      // protect Vt alias below
#undef QKV_BODY
#undef QKV_STAGE

  const int nblk = n0 >> 10;
  if (nblk == 0) {
    // Q: plain bf16 store (q^2 shift cancels in softmax)
    const int nc0 = n0 & 1023;
    #pragma unroll
    for (int nf = 0; nf < 4; ++nf) {
      int n = nc0 + wc + nf * 16 + r;
      float bb = bq[n];
      #pragma unroll
      for (int mf = 0; mf < 4; ++mf) {
        int m = m0 + wr + mf * 16 + q4 * 4;
        f32x4 v = acc[mf][nf];
        #pragma unroll
        for (int i = 0; i < 4; ++i)
          Qb[(size_t)(m + i) * 1024 + n] = f2b(v[i] + bb);
      }
    }
  } else if (nblk == 1) {
    const float sc = LOG2E / temp[0];
    const int nc0 = n0 & 1023;
    float s2a[4][4] = {};
    #pragma unroll
    for (int nf = 0; nf < 4; ++nf) {
      int n = nc0 + wc + nf * 16 + r;
      float bb = bk[n];
      #pragma unroll
      for (int mf = 0; mf < 4; ++mf) {
        int m = m0 + wr + mf * 16 + q4 * 4;
        f32x4 v = acc[mf][nf];
        #pragma unroll
        for (int i = 0; i < 4; ++i) {
          unsigned short os = f2b(v[i] + bb);
          Kb[(size_t)(m + i) * 1024 + n] = os;
          float xb = b2f(os);
          s2a[mf][i] += xb * xb;          // sum of squares of the ROUNDED value
        }
      }
    }
    #pragma unroll
    for (int mf = 0; mf < 4; ++mf)
      #pragma unroll
      for (int i = 0; i < 4; ++i) {
        float v = s2a[mf][i];
        v += __shfl_xor(v, 1, 64);
        v += __shfl_xor(v, 2, 64);
        v += __shfl_xor(v, 4, 64);
        v += __shfl_xor(v, 8, 64);
        s2a[mf][i] = v * sc;
      }
    if (r == 0) {
      int hh2 = (nc0 + wc) >> 6;
      #pragma unroll
      for (int mf = 0; mf < 4; ++mf) {
        int m = m0 + wr + mf * 16 + q4 * 4;
        int bb2 = m >> 11, ss = m & 2047;
        #pragma unroll
        for (int i = 0; i < 4; ++i)
          ks2[(size_t)(bb2 * 16 + hh2) * 2048 + ss + i] = s2a[mf][i];
      }
    }
  } else {
    // ---- V: LDS transpose -> permuted, coalesced VT writes (Vt aliases smem3)
    unsigned short* Vt = smem3;         // [head<2][d<64][G<2 * pos<64], stride 132
    const int c0 = n0 - 2048;
    const int head = w & 1;             // == wc>>6
    #pragma unroll
    for (int nf = 0; nf < 4; ++nf) {
      int c = c0 + wc + nf * 16 + r;
      float bb = bv[c];
      int d = c & 63;
      #pragma unroll
      for (int mf = 0; mf < 4; ++mf) {
        int mloc = wr + mf * 16 + q4 * 4;     // 0..124
        int G = mloc >> 6;
        int k6 = mloc & 63;
        int pos = (k6 >> 5) * 32 + ((k6 & 15) >> 2) * 8 + ((k6 >> 4) & 1) * 4;
        f32x4 v = acc[mf][nf];
        u16x4 pk;
        #pragma unroll
        for (int i = 0; i < 4; ++i) pk[i] = f2b(v[i] + bb);
        *(u16x4*)&Vt[(head * 64 + d) * 132 + G * 64 + pos] = pk;
      }
    }
    __syncthreads();
    int row = t >> 1, ch = t & 1;
    int hd = row >> 6, dd = row & 63;
    int hglob = (c0 >> 6) + hd;
    int bb2 = m0 >> 11, s0 = m0 & 2047;
    unsigned short* dst = &VTo[((size_t)((bb2 * 16 + hglob) * 64 + dd)) * 2048 + s0 + ch * 64];
    const unsigned short* srcL = &Vt[(hd * 64 + dd) * 132 + ch * 64];
    #pragma unroll
    for (int k2 = 0; k2 < 16; ++k2)
      *(u16x4*)&dst[k2 * 4] = *(const u16x4*)&srcL[k2 * 4];
  }
#undef AS3
#undef BS3
}

// ---------------------------------------------------------------- flash
// r13 (proven 48.7us): Block = (bh, 128 q-rows), 4 waves x 32 rows. Grid 512
// blocks, XCD-swizzled (bh == wgid mod 8 -> per-XCD KV 2MB, L2-resident).
// Cross-chunk pipeline: QK^T(c+1) issues before exp(c)+PV(c); accST double-
// state (stA/stB). K ping-pong, V triple; counted vmcnt(4).
__global__ __launch_bounds__(256, 2) void flash_kernel(
    const unsigned short* __restrict__ Qb, const unsigned short* __restrict__ Kb,
    const unsigned short* __restrict__ VT, const float* __restrict__ ks2,
    const float* __restrict__ temp, unsigned short* __restrict__ AO) {
  __shared__ __align__(16) unsigned short Ks[2][64 * 64];   // ping-pong [khalf<2][key<64][dd<32]
  __shared__ __align__(16) unsigned short Vs[3][64 * 64];   // triple, XOR-swizzled 16B units
  __shared__ __align__(16) float KQs[2048];                 // pre-scaled k^2 for this bh
  const int t = threadIdx.x, w = t >> 6, lane = t & 63;
  const int r = lane & 15, q4 = lane >> 4;
  const int wgid = blockIdx.x + 16 * blockIdx.y;   // [0,512)
  const int xcd = wgid & 7, s = wgid >> 3;         // s in [0,64)
  const int bh = xcd + 8 * (s & 3);                // 4 bh per XCD
  const int b = bh >> 4, h = bh & 15;
  const int q0 = (s >> 2) * 128;                   // 16 q-chunks per bh
  const float cc = 2.0f * LOG2E / temp[0];

  bf16x8 qf[2][2];
  #pragma unroll
  for (int qg = 0; qg < 2; ++qg) {
    int sq = q0 + w * 32 + qg * 16 + r;
    const unsigned short* qp = Qb + (size_t)(b * 2048 + sq) * 1024 + h * 64;
    #pragma unroll
    for (int ks = 0; ks < 2; ++ks) qf[qg][ks] = *(const bf16x8*)(qp + ks * 32 + q4 * 8);
  }

  f32x4 accO[2][4] = {};
  f32x4 lsum[2] = {};
  bf16x8 ones;
  #pragma unroll
  for (int j = 0; j < 8; ++j) ones[j] = (short)0x3F80;   // bf16 1.0

  const unsigned short* Kg = Kb + ((size_t)b * 2048) * 1024 + h * 64;
  const unsigned short* Vg = VT + ((size_t)bh * 64) * 2048;
  const float* kqb = ks2 + bh * 2048;

  const unsigned short* kp0 = Kg + (size_t)(t >> 2) * 1024 + (t & 3) * 8;  // khalf 0
  const unsigned short* kp1 = kp0 + 32;                                    // khalf 1
  int dd0 = t >> 3;
  const unsigned short* vp0 = Vg + (size_t)dd0 * 2048 + ((t & 7) ^ (dd0 & 7)) * 8;
  const unsigned short* vp1 = vp0 + (size_t)32 * 2048;

  // ---- prologue: ks2 -> LDS, stage chunk0 -> Ks[0]/Vs[0], chunk1 -> Ks[1]/Vs[1]
  GLD_LDS(kqb + t * 4, &KQs[t * 4]);
  GLD_LDS(kqb + 1024 + t * 4, &KQs[1024 + t * 4]);
  GLD_LDS(kp0, &Ks[0][t * 8]);
  GLD_LDS(kp1, &Ks[0][(256 + t) * 8]);
  GLD_LDS(vp0, &Vs[0][t * 8]);
  GLD_LDS(vp1, &Vs[0][(256 + t) * 8]);
  kp0 += 65536; kp1 += 65536; vp0 += 64; vp1 += 64;
  GLD_LDS(kp0, &Ks[1][t * 8]);
  GLD_LDS(kp1, &Ks[1][(256 + t) * 8]);
  GLD_LDS(vp0, &Vs[1][t * 8]);
  GLD_LDS(vp1, &Vs[1][(256 + t) * 8]);
  kp0 += 65536; kp1 += 65536; vp0 += 64; vp1 += 64;

  const unsigned short* v_cur = &Vs[0][0];
  const unsigned short* v_nxt = &Vs[1][0];
  const unsigned short* v_fre = &Vs[2][0];

  // drain qf(4)+kq(2)+stage0(4) [leaves stage1's 4 in flight], sync, QK(0)
  asm volatile("s_waitcnt vmcnt(4)" ::: "memory");
  __builtin_amdgcn_s_barrier();
  __builtin_amdgcn_sched_barrier(0);

  f32x4 stA[2][4], stB[2][4];
  {
    const f32x4 zz = {};
    __builtin_amdgcn_s_setprio(1);
    #pragma unroll
    for (int ks = 0; ks < 2; ++ks) {
      #pragma unroll
      for (int kfm = 0; kfm < 4; ++kfm) {
        bf16x8 ka = *(const bf16x8*)&Ks[0][(ks * 64 + kfm * 16 + r) * 32 + q4 * 8];
        stA[0][kfm] = __builtin_amdgcn_mfma_f32_16x16x32_bf16(ka, qf[0][ks], ks ? stA[0][kfm] : zz, 0, 0, 0);
        stA[1][kfm] = __builtin_amdgcn_mfma_f32_16x16x32_bf16(ka, qf[1][ks], ks ? stA[1][kfm] : zz, 0, 0, 0);
      }
    }
    __builtin_amdgcn_s_setprio(0);
  }

#define CHUNK_BODY(C, STC, STN)                                               \
  {                                                                           \
    const int c_ = (C);                                                       \
    __builtin_amdgcn_s_barrier();                                             \
    if (c_ < 30) {                                                            \
      unsigned short* kdst = &Ks[(C) & 1][0];                                 \
      GLD_LDS(kp0, kdst + t * 8);                                             \
      GLD_LDS(kp1, kdst + (256 + t) * 8);                                     \
      GLD_LDS(vp0, (unsigned short*)v_fre + t * 8);                           \
      GLD_LDS(vp1, (unsigned short*)v_fre + (256 + t) * 8);                   \
      kp0 += 65536; kp1 += 65536; vp0 += 64; vp1 += 64;                       \
      asm volatile("s_waitcnt vmcnt(4)" ::: "memory");                        \
    } else {                                                                  \
      asm volatile("s_waitcnt vmcnt(0)" ::: "memory");                        \
    }                                                                         \
    __builtin_amdgcn_s_barrier();                                             \
    __builtin_amdgcn_sched_barrier(0);                                        \
    /* QK(c+1): reads Ks[(c+1)&1]; independent of exp/PV below */             \
    if (c_ < 31) {                                                            \
      const unsigned short* krd = &Ks[((C) + 1) & 1][0];                      \
      const f32x4 zz = {};                                                    \
      __builtin_amdgcn_s_setprio(1);                                          \
      _Pragma("unroll")                                                       \
      for (int ks = 0; ks < 2; ++ks) {                                        \
        _Pragma("unroll")                                                     \
        for (int kfm = 0; kfm < 4; ++kfm) {                                   \
          bf16x8 ka = *(const bf16x8*)&krd[(ks * 64 + kfm * 16 + r) * 32 + q4 * 8]; \
          STN[0][kfm] = __builtin_amdgcn_mfma_f32_16x16x32_bf16(ka, qf[0][ks], ks ? STN[0][kfm] : zz, 0, 0, 0); \
          STN[1][kfm] = __builtin_amdgcn_mfma_f32_16x16x32_bf16(ka, qf[1][ks], ks ? STN[1][kfm] : zz, 0, 0, 0); \
        }                                                                     \
      }                                                                       \
      __builtin_amdgcn_s_setprio(0);                                          \
    }                                                                         \
    /* exp(c) from STC + kq(c) (LDS, broadcast) */                            \
    f32x4 kq[4];                                                              \
    _Pragma("unroll")                                                         \
    for (int kfm = 0; kfm < 4; ++kfm)                                         \
      kq[kfm] = *(const f32x4*)&KQs[c_ * 64 + kfm * 16 + q4 * 4];             \
    bf16x8 pf[2][2];                                                          \
    _Pragma("unroll")                                                         \
    for (int qg = 0; qg < 2; ++qg) {                                          \
      _Pragma("unroll")                                                       \
      for (int cb = 0; cb < 2; ++cb) {                                        \
        unsigned int dw[4];                                                   \
        _Pragma("unroll")                                                     \
        for (int half = 0; half < 2; ++half) {                                \
          int kfm = cb * 2 + half;                                            \
          float pp[4];                                                        \
          _Pragma("unroll")                                                   \
          for (int i = 0; i < 4; ++i) {                                       \
            float u = __builtin_fmaf(cc, STC[qg][kfm][i], -kq[kfm][i]);       \
            pp[i] = __builtin_amdgcn_exp2f(u);                                \
          }                                                                   \
          dw[half * 2 + 0] = (fbits(pp[0]) >> 16) | (fbits(pp[1]) & 0xFFFF0000u); \
          dw[half * 2 + 1] = (fbits(pp[2]) >> 16) | (fbits(pp[3]) & 0xFFFF0000u); \
        }                                                                     \
        union { unsigned int d[4]; bf16x8 v; } cv;                            \
        cv.d[0] = dw[0]; cv.d[1] = dw[1]; cv.d[2] = dw[2]; cv.d[3] = dw[3];   \
        pf[qg][cb] = cv.v;                                                    \
      }                                                                       \
    }                                                                         \
    /* O += P.V ; lsum += P.ones (one b128 per V-frag from swizzled Vs) */    \
    __builtin_amdgcn_s_setprio(1);                                            \
    _Pragma("unroll")                                                         \
    for (int cb = 0; cb < 2; ++cb) {                                          \
      lsum[0] = __builtin_amdgcn_mfma_f32_16x16x32_bf16(pf[0][cb], ones, lsum[0], 0, 0, 0); \
      lsum[1] = __builtin_amdgcn_mfma_f32_16x16x32_bf16(pf[1][cb], ones, lsum[1], 0, 0, 0); \
      _Pragma("unroll")                                                       \
      for (int df = 0; df < 4; ++df) {                                        \
        int dloc = df * 16 + r;                                               \
        int un = dloc * 8 + ((cb * 4 + q4) ^ (dloc & 7));                     \
        bf16x8 vb = *(const bf16x8*)&v_cur[un * 8];                           \
        accO[0][df] = __builtin_amdgcn_mfma_f32_16x16x32_bf16(pf[0][cb], vb, accO[0][df], 0, 0, 0); \
        accO[1][df] = __builtin_amdgcn_mfma_f32_16x16x32_bf16(pf[1][cb], vb, accO[1][df], 0, 0, 0); \
      }                                                                       \
    }                                                                         \
    __builtin_amdgcn_s_setprio(0);                                            \
    const unsigned short* tv = v_cur; v_cur = v_nxt; v_nxt = v_fre; v_fre = tv; \
  }

  for (int c2 = 0; c2 < 16; ++c2) {
    CHUNK_BODY(2 * c2, stA, stB)
    CHUNK_BODY(2 * c2 + 1, stB, stA)
  }
#undef CHUNK_BODY

  {
    #pragma unroll
    for (int qg = 0; qg < 2; ++qg) {
      float inv[4];
      #pragma unroll
      for (int i = 0; i < 4; ++i) inv[i] = 1.0f / lsum[qg][i];
      #pragma unroll
      for (int df = 0; df < 4; ++df) {
        int d = df * 16 + r;
        #pragma unroll
        for (int i = 0; i < 4; ++i) {
          int sq = q0 + w * 32 + qg * 16 + q4 * 4 + i;
          AO[(size_t)(b * 2048 + sq) * 1024 + h * 64 + d] = f2b(accO[qg][df][i] * inv[i]);
        }
      }
    }
  }
}

// ------------------------------------------------------------- out GEMM
// 128x64 tile, BK=32 half-steps, 3-buffer 2-deep pipeline, 1 barrier +
// vmcnt(3) per half-step, grid 16x32 = 512 blocks (2/CU).
__global__ __launch_bounds__(256, 2) void gemm_out_kernel(
    const unsigned short* __restrict__ A, const unsigned short* __restrict__ WT,
    const float* __restrict__ bo, float* __restrict__ Out) {
  __shared__ __align__(16) unsigned short osmem[18432];  // A3(12288) B3(6144)
#define AS3o(j) (osmem + (j) * 4096)
#define BS3o(j) (osmem + 12288 + (j) * 2048)
  const int t = threadIdx.x, w = t >> 6, lane = t & 63;
  const int r = lane & 15, q4 = lane >> 4;
  const int m0 = blockIdx.y * 128, n0 = blockIdx.x * 64;
  const int wr = (w >> 1) * 64, wc = (w & 1) * 32;
  const unsigned short* Ag = A + (size_t)m0 * 1024;
  const unsigned short* Wg = WT + (size_t)n0 * 1024;
  const unsigned short* as0 = Ag + (size_t)(t >> 2) * 1024 + (t & 3) * 8;
  const unsigned short* as1 = as0 + (size_t)64 * 1024;
  const unsigned short* bs0 = Wg + (size_t)(t >> 2) * 1024 + (t & 3) * 8;
  f32x4 acc[4][2] = {};

#define OUT_STAGE(J2)                                     \
  {                                                       \
    GLD_LDS(as0, &AS3o(J2)[(w * 64) * 8]);                \
    GLD_LDS(as1, &AS3o(J2)[(256 + w * 64) * 8]);          \
    GLD_LDS(bs0, &BS3o(J2)[(w * 64) * 8]);                \
    as0 += 32; as1 += 32; bs0 += 32;                      \
  }

  OUT_STAGE(0)
  OUT_STAGE(1)
  asm volatile("s_waitcnt vmcnt(3)" ::: "memory");
  __builtin_amdgcn_s_barrier();
  __builtin_amdgcn_sched_barrier(0);

#define OUT_BODY(J, STG, LAST)                                                \
  {                                                                           \
    if (STG) OUT_STAGE(((J) + 2) % 3)                                         \
    bf16x8 af[4], bfr[2];                                                     \
    _Pragma("unroll")                                                         \
    for (int mf = 0; mf < 4; ++mf)                                            \
      af[mf] = *(const bf16x8*)&AS3o(J)[(wr + mf * 16 + r) * 32 + q4 * 8];    \
    _Pragma("unroll")                                                         \
    for (int nf = 0; nf < 2; ++nf)                                            \
      bfr[nf] = *(const bf16x8*)&BS3o(J)[(wc + nf * 16 + r) * 32 + q4 * 8];   \
    _Pragma("unroll")                                                         \
    for (int mf = 0; mf < 4; ++mf)                                            \
      _Pragma("unroll")                                                       \
      for (int nf = 0; nf < 2; ++nf)                                          \
        acc[mf][nf] = __builtin_amdgcn_mfma_f32_16x16x32_bf16(af[mf], bfr[nf], acc[mf][nf], 0, 0, 0); \
    if (STG)       { asm volatile("s_waitcnt vmcnt(3)" ::: "memory"); }       \
    else if (!(LAST)) { asm volatile("s_waitcnt vmcnt(0)" ::: "memory"); }    \
    if (!(LAST)) {                                                            \
      __builtin_amdgcn_s_barrier();                                           \
      __builtin_amdgcn_sched_barrier(0);                                      \
    }                                                                         \
  }

  for (int hh = 0; hh < 5; ++hh) {
    OUT_BODY(0, 1, 0) OUT_BODY(1, 1, 0) OUT_BODY(2, 1, 0)
    OUT_BODY(0, 1, 0) OUT_BODY(1, 1, 0) OUT_BODY(2, 1, 0)
  }
  OUT_BODY(0, 0, 0)
  OUT_BODY(1, 0, 1)
#undef OUT_BODY
#undef OUT_STAGE
#undef AS3o
#undef BS3o

  #pragma unroll
  for (int nf = 0; nf < 2; ++nf) {
    int n = n0 + wc + nf * 16 + r;
    float bb = bo[n];
    #pragma unroll
    for (int mf = 0; mf < 4; ++mf) {
      int m = m0 + wr + mf * 16 + q4 * 4;
      f32x4 v = acc[mf][nf];
      #pragma unroll
      for (int i = 0; i < 4; ++i)
        Out[(size_t)(m + i) * 1024 + n] = v[i] + bb;
    }
  }
}

// ---------------------------------------------------------------- launch
extern "C" void kernel_launch(void* const* d_in, const int* in_sizes, int n_in,
                              void* d_out, int out_size, void* d_ws, size_t ws_size,
                              hipStream_t stream) {
  const float* X    = (const float*)d_in[0];
  const float* wq   = (const float*)d_in[1];
  const float* bq   = (const float*)d_in[2];
  const float* wk   = (const float*)d_in[3];
  const float* bk   = (const float*)d_in[4];
  const float* wv   = (const float*)d_in[5];
  const float* bv   = (const float*)d_in[6];
  const float* wo   = (const float*)d_in[7];
  const float* bo   = (const float*)d_in[8];
  const float* temp = (const float*)d_in[9];
  float* Out = (float*)d_out;

  char* ws = (char*)d_ws;
  unsigned short* Xb    = (unsigned short*)ws; ws += (size_t)4096 * 1024 * 2;
  unsigned short* WTqkv = (unsigned short*)ws; ws += (size_t)3072 * 1024 * 2;
  unsigned short* WTo   = (unsigned short*)ws; ws += (size_t)1024 * 1024 * 2;
  unsigned short* Qb    = (unsigned short*)ws; ws += (size_t)4096 * 1024 * 2;
  unsigned short* Kb    = (unsigned short*)ws; ws += (size_t)4096 * 1024 * 2;
  unsigned short* VT    = (unsigned short*)ws; ws += (size_t)4096 * 1024 * 2;
  float* ks2 = (float*)ws; ws += (size_t)65536 * 4;
  unsigned short* AO = Xb;   // Xb dead after gemm_qkv; reuse for flash output

  prep_kernel<<<dim3(16, 16, 5), 256, 0, stream>>>(X, wq, wk, wv, wo, Xb, WTqkv, WTo);
  gemm_qkv_kernel<<<dim3(24, 32), 256, 0, stream>>>(Xb, WTqkv, bq, bk, bv, temp, Qb, Kb, VT, ks2);
  flash_kernel<<<dim3(16, 32), 256, 0, stream>>>(Qb, Kb, VT, ks2, temp, AO);
  gemm_out_kernel<<<dim3(16, 32), 256, 0, stream>>>(AO, WTo, bo, Out);
}